// Round 2
// baseline (191.087 us; speedup 1.0000x reference)
//
#include <hip/hip_runtime.h>
#include <math.h>

// Static graph dims
#define BATCH   16384
#define IN_DIM  512
#define NH      128
#define NO      256
#define L2E     1.4426950408889634f

__device__ __forceinline__ float fast_rcp(float x) { return __builtin_amdgcn_rcpf(x); }
__device__ __forceinline__ float fast_exp2(float x) {
#if __has_builtin(__builtin_amdgcn_exp2f)
    return __builtin_amdgcn_exp2f(x);
#else
    return exp2f(x);
#endif
}
__device__ __forceinline__ int rfl(int v) { return __builtin_amdgcn_readfirstlane(v); }

__device__ __forceinline__ float fast_tanh(float z) {
    float ex = fast_exp2(2.f * L2E * z);
    return 1.f - 2.f * fast_rcp(1.f + ex);
}
__device__ __forceinline__ float fast_sig(float z) {
    float ex = fast_exp2(-L2E * z);
    return fast_rcp(1.f + ex);
}
__device__ __forceinline__ float act_k(int a) {
    return (a == 2) ? (2.f * L2E) : ((a == 4) ? -L2E : 0.f);
}

// act ids: 1=identity, 2=tanh, 3=relu, 4=sigmoid. `a` is wave-uniform -> scalar branch;
// identity/relu skip the quarter-rate exp2/rcp entirely.
__device__ __forceinline__ float act1(float z, int a) {
    if (a == 2) return fast_tanh(z);
    if (a == 4) return fast_sig(z);
    if (a == 3) return fmaxf(z, 0.f);
    return z;
}

__device__ __forceinline__ unsigned int f2bf_rne(float f) {
    unsigned int u = __float_as_uint(f);
    return (u + 0x7FFFu + ((u >> 16) & 1u)) >> 16;
}
__device__ __forceinline__ float bf2f(unsigned short h) { return __uint_as_float(((unsigned int)h) << 16); }
__device__ __forceinline__ unsigned short f2bf16s(float f) { return (unsigned short)f2bf_rne(f); }

__device__ __forceinline__ int lower_bound_dev(const int* __restrict__ arr, int n, int v) {
    int lo = 0, hi = n;
    while (lo < hi) { int m = (lo + hi) >> 1; if (arr[m] < v) lo = m + 1; else hi = m; }
    return lo;
}

// ---------------- prep: CSR offsets + packed int4 edge records (tiny) ----------------
__global__ __launch_bounds__(256)
void prep_edges(const int* __restrict__ rows_h, const int* __restrict__ cols_h,
                const int* __restrict__ acts_h, const float* __restrict__ wh,
                const int* __restrict__ rows_o, const int* __restrict__ cols_o,
                const int* __restrict__ acts_o, const float* __restrict__ wo,
                int Eh, int Eo,
                int* __restrict__ offs_h, int* __restrict__ offs_o,
                int4* __restrict__ packed_h, int4* __restrict__ packed_o) {
    int t = blockIdx.x * 256 + threadIdx.x;
    if (t <= NH) offs_h[t] = lower_bound_dev(rows_h, Eh, t);
    else if (t <= NH + 1 + NO) offs_o[t - (NH + 1)] = lower_bound_dev(rows_o, Eo, t - (NH + 1));
    int u = t - (NH + 1 + NO + 1);
    if (u >= 0 && u < Eh)
        packed_h[u] = make_int4(cols_h[u], acts_h[u], __float_as_int(wh[u]), 0);
    u -= Eh;
    if (u >= 0 && u < Eo)
        packed_o[u] = make_int4(cols_o[u], acts_o[u], __float_as_int(wo[u]), 0);
}

// ---------------- fused main: 64 batches/block, whole graph in one pass ----------------
// LDS: X bf16 [64][514] = 65792 B, H f32 [128][65] = 33280 B at +65792 -> 99072 B total.
// OBT (output transpose) overlays X+H after compute (66540 B max).
// X read X[lane*514+col]: dword stride 257 == 1 (mod 32) -> conflict-free.
// H  read/write [r][lane]: lane-contiguous -> conflict-free.
#define FXS   514
#define FHS   65
#define FOBS  260
#define FLDSZ 99072
__global__ __launch_bounds__(1024)
void fused_main(const float* __restrict__ x,
                const int* __restrict__ offs_h, const int4* __restrict__ packed_h,
                const int* __restrict__ offs_o, const int4* __restrict__ packed_o,
                float* __restrict__ out)
{
    extern __shared__ char lds[];
    unsigned short* X   = (unsigned short*)lds;
    float*          H   = (float*)(lds + 65792);
    float*          OBT = (float*)lds;
    const int tid  = threadIdx.x;
    const int lane = tid & 63;
    const int wv   = tid >> 6;
    const int rb   = blockIdx.x * 64;

    // ---- load + bf16-convert x slab: 64 rows x 512 cols, coalesced float4 ----
    {
        const float4* xv = (const float4*)(x + (size_t)rb * IN_DIM);
        #pragma unroll
        for (int kk = 0; kk < 8; ++kk) {
            int v = tid + kk * 1024;
            int r = v >> 7, i = v & 127;
            float4 f = xv[v];
            unsigned int lo = f2bf_rne(f.x) | (f2bf_rne(f.y) << 16);
            unsigned int hi = f2bf_rne(f.z) | (f2bf_rne(f.w) << 16);
            unsigned int* dst = (unsigned int*)&X[r * FXS + i * 4];
            dst[0] = lo; dst[1] = hi;
        }
    }
    __syncthreads();

    // ---- hidden: wave wv owns rows wv*8..wv*8+7, 1 batch elem/lane ----
    #pragma unroll
    for (int rr = 0; rr < NH / 16; ++rr) {
        const int r  = wv * (NH / 16) + rr;
        const int e0 = rfl(offs_h[r]);
        const int e1 = rfl(offs_h[r + 1]);
        float acc = 0.f;
        #pragma unroll 4
        for (int e = e0; e < e1; ++e) {
            int4 p  = packed_h[e];                 // uniform addr -> s_load_dwordx4
            int col = rfl(p.x);
            int a   = rfl(p.y);
            float w = __int_as_float(rfl(p.z));
            acc += act1(bf2f(X[lane * FXS + col]) * w, a);
        }
        H[r * FHS + lane] = acc;
    }
    __syncthreads();

    // ---- output: wave wv owns rows wv*16..wv*16+15 ----
    float res[NO / 16];
    #pragma unroll
    for (int rr = 0; rr < NO / 16; ++rr) {
        const int r  = wv * (NO / 16) + rr;
        const int e0 = rfl(offs_o[r]);
        const int e1 = rfl(offs_o[r + 1]);
        float acc = 0.f;
        #pragma unroll 4
        for (int e = e0; e < e1; ++e) {
            int4 p  = packed_o[e];
            int col = rfl(p.x);
            int a   = rfl(p.y);
            float w = __int_as_float(rfl(p.z));
            float v = (col < IN_DIM) ? bf2f(X[lane * FXS + col])
                                     : H[(col - IN_DIM) * FHS + lane];
            acc += act1(v * w, a);
        }
        res[rr] = fast_tanh(acc);
    }
    __syncthreads();

    // ---- transpose via LDS (overlays X/H) then coalesced writeout ----
    #pragma unroll
    for (int rr = 0; rr < NO / 16; ++rr)
        OBT[lane * FOBS + wv * (NO / 16) + rr] = res[rr];
    __syncthreads();
    #pragma unroll
    for (int kk = 0; kk < 4; ++kk) {
        int v  = tid + kk * 1024;
        int c4 = v & 63;     // 64 lanes cover one batch's full 256-float row (1 KB)
        int b  = v >> 6;
        float4 o = *(const float4*)&OBT[b * FOBS + c4 * 4];
        *(float4*)&out[(size_t)(rb + b) * NO + c4 * 4] = o;
    }
}

// =============== fallback: single fused kernel, no workspace ===============
#define FT      1024
#define FBPB    64
#define FHS2    65
#define FOBTS   260
#define FLDS    (99072 + 1544)
__device__ __forceinline__ float edge_act2(float z, int a, float k) {
    float ex = fast_exp2(k * z);
    float rc = fast_rcp(1.f + ex);
    return (a == 2) ? (1.f - 2.f * rc) : ((a == 4) ? rc : ((a == 3) ? fmaxf(z, 0.f) : z));
}
__global__ __launch_bounds__(FT)
void wann_fused(const float* __restrict__ x,
                const int* __restrict__ rows_h, const int* __restrict__ cols_h,
                const int* __restrict__ acts_h, const float* __restrict__ wh,
                const int* __restrict__ rows_o, const int* __restrict__ cols_o,
                const int* __restrict__ acts_o, const float* __restrict__ wo,
                float* __restrict__ out, int Eh, int Eo)
{
    extern __shared__ char lds[];
    unsigned short* X   = (unsigned short*)lds;
    float*          H   = (float*)(lds + 65792);
    float*          OBT = (float*)lds;
    int*            offsH = (int*)(lds + 99072);
    int*            offsO = offsH + (NH + 1);
    const int tid  = threadIdx.x;
    const int lane = tid & 63;
    const int wv   = tid >> 6;
    const int rb   = blockIdx.x * FBPB;
    const int* wh_i = (const int*)wh;
    const int* wo_i = (const int*)wo;
    {
        const float4* xv = (const float4*)(x + (size_t)rb * IN_DIM);
        #pragma unroll
        for (int kk = 0; kk < (FBPB * IN_DIM / 4) / FT; ++kk) {
            int v = tid + kk * FT;
            int r = v >> 7, i = v & 127;
            float4 f = xv[v];
            unsigned int lo = (unsigned int)f2bf16s(f.x) | ((unsigned int)f2bf16s(f.y) << 16);
            unsigned int hi = (unsigned int)f2bf16s(f.z) | ((unsigned int)f2bf16s(f.w) << 16);
            unsigned int* dst = (unsigned int*)&X[r * FXS + i * 4];
            dst[0] = lo; dst[1] = hi;
        }
    }
    if (tid <= NH) offsH[tid] = lower_bound_dev(rows_h, Eh, tid);
    else if (tid <= NH + 1 + NO) offsO[tid - (NH + 1)] = lower_bound_dev(rows_o, Eo, tid - (NH + 1));
    __syncthreads();
    for (int r = wv * (NH / 16); r < (wv + 1) * (NH / 16); ++r) {
        const int e0 = rfl(offsH[r]); const int e1 = rfl(offsH[r + 1]);
        float acc = 0.f;
        #pragma unroll 4
        for (int e = e0; e < e1; ++e) {
            int col = rfl(cols_h[e]); int a = rfl(acts_h[e]);
            float w = __int_as_float(rfl(wh_i[e]));
            acc += edge_act2(bf2f(X[lane * FXS + col]) * w, a, act_k(a));
        }
        H[r * FHS2 + lane] = acc;
    }
    __syncthreads();
    float res[NO / 16];
    #pragma unroll
    for (int rr = 0; rr < NO / 16; ++rr) {
        const int r = wv * (NO / 16) + rr;
        const int e0 = rfl(offsO[r]); const int e1 = rfl(offsO[r + 1]);
        float acc = 0.f;
        #pragma unroll 4
        for (int e = e0; e < e1; ++e) {
            int col = rfl(cols_o[e]); int a = rfl(acts_o[e]);
            float w = __int_as_float(rfl(wo_i[e]));
            float v = (col < IN_DIM) ? bf2f(X[lane * FXS + col]) : H[(col - IN_DIM) * FHS2 + lane];
            acc += edge_act2(v * w, a, act_k(a));
        }
        res[rr] = fast_tanh(acc);
    }
    __syncthreads();
    #pragma unroll
    for (int rr = 0; rr < NO / 16; ++rr)
        OBT[lane * FOBTS + wv * (NO / 16) + rr] = res[rr];
    __syncthreads();
    #pragma unroll
    for (int kk = 0; kk < (FBPB * NO / 4) / FT; ++kk) {
        int v = tid + kk * FT;
        int c4 = v & 63, b = v >> 6;
        float4 o = *(const float4*)&OBT[b * FOBTS + c4 * 4];
        *(float4*)&out[(size_t)(rb + b) * NO + c4 * 4] = o;
    }
}

extern "C" void kernel_launch(void* const* d_in, const int* in_sizes, int n_in,
                              void* d_out, int out_size, void* d_ws, size_t ws_size,
                              hipStream_t stream) {
    const float* x      = (const float*)d_in[0];
    const float* wh     = (const float*)d_in[1];
    const float* wo     = (const float*)d_in[2];
    const int*   rows_h = (const int*)d_in[3];
    const int*   cols_h = (const int*)d_in[4];
    const int*   acts_h = (const int*)d_in[5];
    const int*   rows_o = (const int*)d_in[6];
    const int*   cols_o = (const int*)d_in[7];
    const int*   acts_o = (const int*)d_in[8];
    float*       out    = (float*)d_out;

    const int Eh = in_sizes[1];
    const int Eo = in_sizes[2];

    // ws layout: [offs_h@0][offs_o@1024][packed_h@4096][packed_o]
    char* ws = (char*)d_ws;
    int*  offs_h   = (int*)ws;
    int*  offs_o   = (int*)(ws + 1024);
    int4* packed_h = (int4*)(ws + 4096);
    int4* packed_o = packed_h + Eh;
    size_t need = 4096 + (size_t)(Eh + Eo) * 16;

    if (ws_size >= need) {
        const int ntasks = (NH + 1) + (NO + 1) + Eh + Eo;
        prep_edges<<<(ntasks + 255) / 256, 256, 0, stream>>>(
            rows_h, cols_h, acts_h, wh, rows_o, cols_o, acts_o, wo,
            Eh, Eo, offs_h, offs_o, packed_h, packed_o);
        fused_main<<<BATCH / 64, 1024, FLDSZ, stream>>>(
            x, offs_h, packed_h, offs_o, packed_o, out);
    } else {
        wann_fused<<<BATCH / FBPB, FT, FLDS, stream>>>(
            x, rows_h, cols_h, acts_h, wh, rows_o, cols_o, acts_o, wo, out, Eh, Eo);
    }
}

// Round 3
// 159.482 us; speedup vs baseline: 1.1982x; 1.1982x over previous
//
#include <hip/hip_runtime.h>
#include <math.h>

// Static graph dims
#define BATCH   16384
#define IN_DIM  512
#define NH      128
#define NO      256
#define L2E     1.4426950408889634f

__device__ __forceinline__ float fast_rcp(float x) { return __builtin_amdgcn_rcpf(x); }
__device__ __forceinline__ float fast_exp2(float x) {
#if __has_builtin(__builtin_amdgcn_exp2f)
    return __builtin_amdgcn_exp2f(x);
#else
    return exp2f(x);
#endif
}
__device__ __forceinline__ int rfl(int v) { return __builtin_amdgcn_readfirstlane(v); }

__device__ __forceinline__ float fast_tanh(float z) {
    float ex = fast_exp2(2.f * L2E * z);
    return 1.f - 2.f * fast_rcp(1.f + ex);
}
__device__ __forceinline__ float fast_sig(float z) {
    float ex = fast_exp2(-L2E * z);
    return fast_rcp(1.f + ex);
}
__device__ __forceinline__ float act_k(int a) {
    return (a == 2) ? (2.f * L2E) : ((a == 4) ? -L2E : 0.f);
}

__device__ __forceinline__ unsigned int f2bf_rne(float f) {
    unsigned int u = __float_as_uint(f);
    return (u + 0x7FFFu + ((u >> 16) & 1u)) >> 16;
}
__device__ __forceinline__ float bf2f(unsigned short h) { return __uint_as_float(((unsigned int)h) << 16); }
__device__ __forceinline__ unsigned short f2bf16s(float f) { return (unsigned short)f2bf_rne(f); }

__device__ __forceinline__ int lower_bound_dev(const int* __restrict__ arr, int n, int v) {
    int lo = 0, hi = n;
    while (lo < hi) { int m = (lo + hi) >> 1; if (arr[m] < v) lo = m + 1; else hi = m; }
    return lo;
}

// ---------------- prep: per-row act-sorted meta {col,w} + 4-way boundaries ----------------
// one wave per row; ballot/popcount stable partition by act id.
__global__ __launch_bounds__(512)
void prep_sorted(const int* __restrict__ rows_h, const int* __restrict__ cols_h,
                 const int* __restrict__ acts_h, const float* __restrict__ wh,
                 const int* __restrict__ rows_o, const int* __restrict__ cols_o,
                 const int* __restrict__ acts_o, const float* __restrict__ wo,
                 int Eh, int Eo,
                 int* __restrict__ offs4_h, int* __restrict__ offs4_o,
                 uint2* __restrict__ meta_h, uint2* __restrict__ meta_o)
{
    const int lane = (int)(threadIdx.x & 63);
    const int wid  = (int)((blockIdx.x * blockDim.x + threadIdx.x) >> 6);
    if (wid >= NH + NO) {
        if (wid == NH + NO && lane == 0) { offs4_h[NH * 4] = Eh; offs4_o[NO * 4] = Eo; }
        return;
    }
    const bool isH = wid < NH;
    const int r = isH ? wid : wid - NH;
    const int*   rows = isH ? rows_h : rows_o;
    const int*   cols = isH ? cols_h : cols_o;
    const int*   acts = isH ? acts_h : acts_o;
    const float* ww   = isH ? wh : wo;
    const int    E    = isH ? Eh : Eo;
    int*   off4 = isH ? offs4_h : offs4_o;
    uint2* meta = isH ? meta_h : meta_o;

    const int e0 = lower_bound_dev(rows, E, r);
    const int e1 = lower_bound_dev(rows, E, r + 1);
    const int n  = e1 - e0;
    const unsigned long long ltmask = (1ull << lane) - 1ull;

    // pass 1: count acts
    int cnt1 = 0, cnt2 = 0, cnt3 = 0;
    for (int g = 0; g < n; g += 64) {
        int a = 0;
        if (g + lane < n) a = acts[e0 + g + lane];
        cnt1 += __popcll(__ballot(a == 1));
        cnt2 += __popcll(__ballot(a == 2));
        cnt3 += __popcll(__ballot(a == 3));
    }
    if (lane == 0) {
        off4[r * 4 + 0] = e0;
        off4[r * 4 + 1] = e0 + cnt1;
        off4[r * 4 + 2] = e0 + cnt1 + cnt2;
        off4[r * 4 + 3] = e0 + cnt1 + cnt2 + cnt3;
    }
    // pass 2: stable scatter per act
    int pos1 = e0;
    int pos2 = e0 + cnt1;
    int pos3 = e0 + cnt1 + cnt2;
    int pos4 = e0 + cnt1 + cnt2 + cnt3;
    for (int g = 0; g < n; g += 64) {
        const bool valid = (g + lane < n);
        int a = 0; unsigned c = 0, wb = 0;
        if (valid) {
            int e = e0 + g + lane;
            a  = acts[e];
            c  = (unsigned)cols[e];
            wb = __float_as_uint(ww[e]);
        }
        unsigned long long m1 = __ballot(a == 1);
        unsigned long long m2 = __ballot(a == 2);
        unsigned long long m3 = __ballot(a == 3);
        unsigned long long m4 = __ballot(a == 4);
        if (a == 1) meta[pos1 + __popcll(m1 & ltmask)] = make_uint2(c, wb);
        if (a == 2) meta[pos2 + __popcll(m2 & ltmask)] = make_uint2(c, wb);
        if (a == 3) meta[pos3 + __popcll(m3 & ltmask)] = make_uint2(c, wb);
        if (a == 4) meta[pos4 + __popcll(m4 & ltmask)] = make_uint2(c, wb);
        pos1 += __popcll(m1); pos2 += __popcll(m2);
        pos3 += __popcll(m3); pos4 += __popcll(m4);
    }
}

// ---------------- fused main: 64 batches/block, whole graph in one pass ----------------
// LDS: X bf16 [64][514] = 65792 B + H f32 [128][65] = 33280 B -> 99072 B.
// Inner edge loops: DS-only memory (metadata via v_readlane broadcast) -> no lgkm
// pollution from s_load; act-sorted runs -> branch-free bodies.
#define FXS   514
#define FHS   65
#define MLDS  99072

template<bool OUT>
__device__ __forceinline__ float row_accum(const unsigned short* __restrict__ X,
                                           const float* __restrict__ H,
                                           const uint2* __restrict__ meta,
                                           const int* __restrict__ offs4,
                                           int r, int lane)
{
    const int b0 = rfl(offs4[r * 4 + 0]);
    const int b1 = rfl(offs4[r * 4 + 1]);
    const int b2 = rfl(offs4[r * 4 + 2]);
    const int b3 = rfl(offs4[r * 4 + 3]);
    const int b4 = rfl(offs4[r * 4 + 4]);
    const int n  = b4 - b0;
    float acc = 0.f;
    for (int g = 0; g < n; g += 64) {
        int idx = g + lane; if (idx > n - 1) idx = n - 1;
        const uint2 mv = meta[b0 + idx];               // coalesced; lane j holds edge g+j
        const int ga = b0 + g;
        const int ge = (b4 < ga + 64) ? b4 : (ga + 64);

        // act 1: identity (pure fmac)
        {
            const int lo = (b0 > ga) ? b0 : ga, hi = (b1 < ge) ? b1 : ge;
            #pragma unroll 4
            for (int j = lo; j < hi; ++j) {
                int jj = j - ga;
                int col = __builtin_amdgcn_readlane((int)mv.x, jj);
                float w = __uint_as_float((unsigned)__builtin_amdgcn_readlane((int)mv.y, jj));
                float v = (OUT && col >= IN_DIM) ? H[(col - IN_DIM) * FHS + lane]
                                                 : bf2f(X[lane * FXS + col]);
                acc = fmaf(v, w, acc);
            }
        }
        // act 2: tanh
        {
            const int lo = (b1 > ga) ? b1 : ga, hi = (b2 < ge) ? b2 : ge;
            #pragma unroll 4
            for (int j = lo; j < hi; ++j) {
                int jj = j - ga;
                int col = __builtin_amdgcn_readlane((int)mv.x, jj);
                float w = __uint_as_float((unsigned)__builtin_amdgcn_readlane((int)mv.y, jj));
                float v = (OUT && col >= IN_DIM) ? H[(col - IN_DIM) * FHS + lane]
                                                 : bf2f(X[lane * FXS + col]);
                acc += fast_tanh(v * w);
            }
        }
        // act 3: relu
        {
            const int lo = (b2 > ga) ? b2 : ga, hi = (b3 < ge) ? b3 : ge;
            #pragma unroll 4
            for (int j = lo; j < hi; ++j) {
                int jj = j - ga;
                int col = __builtin_amdgcn_readlane((int)mv.x, jj);
                float w = __uint_as_float((unsigned)__builtin_amdgcn_readlane((int)mv.y, jj));
                float v = (OUT && col >= IN_DIM) ? H[(col - IN_DIM) * FHS + lane]
                                                 : bf2f(X[lane * FXS + col]);
                acc += fmaxf(v * w, 0.f);
            }
        }
        // act 4: sigmoid
        {
            const int lo = (b3 > ga) ? b3 : ga, hi = ge;
            #pragma unroll 4
            for (int j = lo; j < hi; ++j) {
                int jj = j - ga;
                int col = __builtin_amdgcn_readlane((int)mv.x, jj);
                float w = __uint_as_float((unsigned)__builtin_amdgcn_readlane((int)mv.y, jj));
                float v = (OUT && col >= IN_DIM) ? H[(col - IN_DIM) * FHS + lane]
                                                 : bf2f(X[lane * FXS + col]);
                acc += fast_sig(v * w);
            }
        }
    }
    return acc;
}

__global__ __launch_bounds__(1024)
void fused_main(const float* __restrict__ x,
                const int* __restrict__ offs4_h, const uint2* __restrict__ meta_h,
                const int* __restrict__ offs4_o, const uint2* __restrict__ meta_o,
                float* __restrict__ out)
{
    extern __shared__ char lds[];
    unsigned short* X   = (unsigned short*)lds;
    float*          H   = (float*)(lds + 65792);
    float*          OBT = (float*)lds;                  // overlays X/H after compute
    const int tid  = (int)threadIdx.x;
    const int lane = tid & 63;
    const int wv   = tid >> 6;
    const int rb   = (int)blockIdx.x * 64;

    // ---- load + bf16-convert x slab: 64 rows x 512 cols, coalesced float4 ----
    {
        const float4* xv = (const float4*)(x + (size_t)rb * IN_DIM);
        #pragma unroll
        for (int kk = 0; kk < 8; ++kk) {
            int v = tid + kk * 1024;
            int rr = v >> 7, i = v & 127;
            float4 f = xv[v];
            unsigned int lo = f2bf_rne(f.x) | (f2bf_rne(f.y) << 16);
            unsigned int hi = f2bf_rne(f.z) | (f2bf_rne(f.w) << 16);
            unsigned int* dst = (unsigned int*)&X[rr * FXS + i * 4];
            dst[0] = lo; dst[1] = hi;
        }
    }
    __syncthreads();

    // ---- hidden: wave wv owns rows wv*8..+7, 1 batch elem/lane ----
    #pragma unroll
    for (int q = 0; q < NH / 16; ++q) {
        const int r = wv * (NH / 16) + q;
        H[r * FHS + lane] = row_accum<false>(X, H, meta_h, offs4_h, r, lane);
    }
    __syncthreads();

    // ---- output: wave wv owns rows wv*16..+15 ----
    float res[NO / 16];
    #pragma unroll
    for (int q = 0; q < NO / 16; ++q) {
        const int r = wv * (NO / 16) + q;
        res[q] = fast_tanh(row_accum<true>(X, H, meta_o, offs4_o, r, lane));
    }
    __syncthreads();

    // ---- transpose via LDS (stride 65: bank = r + lane -> conflict-free) ----
    #pragma unroll
    for (int q = 0; q < NO / 16; ++q)
        OBT[(wv * (NO / 16) + q) * FHS + lane] = res[q];
    __syncthreads();
    // lanes read scattered cols (c = lane + i*64 -> bank = lane), stores lane-contiguous
    #pragma unroll
    for (int s = 0; s < 4; ++s) {
        const int b = wv * 4 + s;
        #pragma unroll
        for (int i = 0; i < 4; ++i) {
            const int c = lane + i * 64;
            out[(size_t)(rb + b) * NO + c] = OBT[c * FHS + b];
        }
    }
}

// =============== fallback: single fused kernel, no workspace ===============
#define FT      1024
#define FBPB    64
#define FHS2    65
#define FOBTS   260
#define FLDS    (99072 + 1544)
__device__ __forceinline__ float edge_act2(float z, int a, float k) {
    float ex = fast_exp2(k * z);
    float rc = fast_rcp(1.f + ex);
    return (a == 2) ? (1.f - 2.f * rc) : ((a == 4) ? rc : ((a == 3) ? fmaxf(z, 0.f) : z));
}
__global__ __launch_bounds__(FT)
void wann_fused(const float* __restrict__ x,
                const int* __restrict__ rows_h, const int* __restrict__ cols_h,
                const int* __restrict__ acts_h, const float* __restrict__ wh,
                const int* __restrict__ rows_o, const int* __restrict__ cols_o,
                const int* __restrict__ acts_o, const float* __restrict__ wo,
                float* __restrict__ out, int Eh, int Eo)
{
    extern __shared__ char lds[];
    unsigned short* X   = (unsigned short*)lds;
    float*          H   = (float*)(lds + 65792);
    float*          OBT = (float*)lds;
    int*            offsH = (int*)(lds + 99072);
    int*            offsO = offsH + (NH + 1);
    const int tid  = threadIdx.x;
    const int lane = tid & 63;
    const int wv   = tid >> 6;
    const int rb   = blockIdx.x * FBPB;
    const int* wh_i = (const int*)wh;
    const int* wo_i = (const int*)wo;
    {
        const float4* xv = (const float4*)(x + (size_t)rb * IN_DIM);
        #pragma unroll
        for (int kk = 0; kk < (FBPB * IN_DIM / 4) / FT; ++kk) {
            int v = tid + kk * FT;
            int r = v >> 7, i = v & 127;
            float4 f = xv[v];
            unsigned int lo = (unsigned int)f2bf16s(f.x) | ((unsigned int)f2bf16s(f.y) << 16);
            unsigned int hi = (unsigned int)f2bf16s(f.z) | ((unsigned int)f2bf16s(f.w) << 16);
            unsigned int* dst = (unsigned int*)&X[r * FXS + i * 4];
            dst[0] = lo; dst[1] = hi;
        }
    }
    if (tid <= NH) offsH[tid] = lower_bound_dev(rows_h, Eh, tid);
    else if (tid <= NH + 1 + NO) offsO[tid - (NH + 1)] = lower_bound_dev(rows_o, Eo, tid - (NH + 1));
    __syncthreads();
    for (int r = wv * (NH / 16); r < (wv + 1) * (NH / 16); ++r) {
        const int e0 = rfl(offsH[r]); const int e1 = rfl(offsH[r + 1]);
        float acc = 0.f;
        #pragma unroll 4
        for (int e = e0; e < e1; ++e) {
            int col = rfl(cols_h[e]); int a = rfl(acts_h[e]);
            float w = __int_as_float(rfl(wh_i[e]));
            acc += edge_act2(bf2f(X[lane * FXS + col]) * w, a, act_k(a));
        }
        H[r * FHS2 + lane] = acc;
    }
    __syncthreads();
    float res[NO / 16];
    #pragma unroll
    for (int rr = 0; rr < NO / 16; ++rr) {
        const int r = wv * (NO / 16) + rr;
        const int e0 = rfl(offsO[r]); const int e1 = rfl(offsO[r + 1]);
        float acc = 0.f;
        #pragma unroll 4
        for (int e = e0; e < e1; ++e) {
            int col = rfl(cols_o[e]); int a = rfl(acts_o[e]);
            float w = __int_as_float(rfl(wo_i[e]));
            float v = (col < IN_DIM) ? bf2f(X[lane * FXS + col]) : H[(col - IN_DIM) * FHS2 + lane];
            acc += edge_act2(v * w, a, act_k(a));
        }
        res[rr] = fast_tanh(acc);
    }
    __syncthreads();
    #pragma unroll
    for (int rr = 0; rr < NO / 16; ++rr)
        OBT[lane * FOBTS + wv * (NO / 16) + rr] = res[rr];
    __syncthreads();
    #pragma unroll
    for (int kk = 0; kk < (FBPB * NO / 4) / FT; ++kk) {
        int v = tid + kk * FT;
        int c4 = v & 63, b = v >> 6;
        float4 o = *(const float4*)&OBT[b * FOBTS + c4 * 4];
        *(float4*)&out[(size_t)(rb + b) * NO + c4 * 4] = o;
    }
}

extern "C" void kernel_launch(void* const* d_in, const int* in_sizes, int n_in,
                              void* d_out, int out_size, void* d_ws, size_t ws_size,
                              hipStream_t stream) {
    const float* x      = (const float*)d_in[0];
    const float* wh     = (const float*)d_in[1];
    const float* wo     = (const float*)d_in[2];
    const int*   rows_h = (const int*)d_in[3];
    const int*   cols_h = (const int*)d_in[4];
    const int*   acts_h = (const int*)d_in[5];
    const int*   rows_o = (const int*)d_in[6];
    const int*   cols_o = (const int*)d_in[7];
    const int*   acts_o = (const int*)d_in[8];
    float*       out    = (float*)d_out;

    const int Eh = in_sizes[1];
    const int Eo = in_sizes[2];

    // ws layout: [offs4_h @0 (NH*4+1 ints)][offs4_o @4096 (NO*4+1)][meta_h @12288][meta_o]
    char*  ws      = (char*)d_ws;
    int*   offs4_h = (int*)ws;
    int*   offs4_o = (int*)(ws + 4096);
    uint2* meta_h  = (uint2*)(ws + 12288);
    uint2* meta_o  = meta_h + Eh;
    size_t need = 12288 + (size_t)(Eh + Eo) * 8;

    if (ws_size >= need) {
        const int nwaves = NH + NO + 1;                       // one wave per row + sentinel
        const int blocks = (nwaves * 64 + 511) / 512;
        prep_sorted<<<blocks, 512, 0, stream>>>(
            rows_h, cols_h, acts_h, wh, rows_o, cols_o, acts_o, wo,
            Eh, Eo, offs4_h, offs4_o, meta_h, meta_o);
        fused_main<<<BATCH / 64, 1024, MLDS, stream>>>(
            x, offs4_h, meta_h, offs4_o, meta_o, out);
    } else {
        wann_fused<<<BATCH / FBPB, FT, FLDS, stream>>>(
            x, rows_h, cols_h, acts_h, wh, rows_o, cols_o, acts_o, wo, out, Eh, Eo);
    }
}

// Round 4
// 144.132 us; speedup vs baseline: 1.3258x; 1.1065x over previous
//
#include <hip/hip_runtime.h>
#include <math.h>

// Static graph dims
#define BATCH   16384
#define IN_DIM  512
#define NH      128
#define NO      256
#define L2E     1.4426950408889634f

__device__ __forceinline__ float fast_rcp(float x) { return __builtin_amdgcn_rcpf(x); }
__device__ __forceinline__ float fast_exp2(float x) {
#if __has_builtin(__builtin_amdgcn_exp2f)
    return __builtin_amdgcn_exp2f(x);
#else
    return exp2f(x);
#endif
}
__device__ __forceinline__ int rfl(int v) { return __builtin_amdgcn_readfirstlane(v); }
__device__ __forceinline__ int rdl(int v, int l) { return __builtin_amdgcn_readlane(v, l); }

__device__ __forceinline__ float fast_tanh(float z) {
    float ex = fast_exp2(2.f * L2E * z);
    return 1.f - 2.f * fast_rcp(1.f + ex);
}
__device__ __forceinline__ float act_k(int a) {
    return (a == 2) ? (2.f * L2E) : ((a == 4) ? -L2E : 0.f);
}

__device__ __forceinline__ unsigned int f2bf_rne(float f) {
    unsigned int u = __float_as_uint(f);
    return (u + 0x7FFFu + ((u >> 16) & 1u)) >> 16;
}
__device__ __forceinline__ float bf2f(unsigned short h) { return __uint_as_float(((unsigned int)h) << 16); }
__device__ __forceinline__ unsigned short f2bf16s(float f) { return (unsigned short)f2bf_rne(f); }

__device__ __forceinline__ int lower_bound_dev(const int* __restrict__ arr, int n, int v) {
    int lo = 0, hi = n;
    while (lo < hi) { int m = (lo + hi) >> 1; if (arr[m] < v) lo = m + 1; else hi = m; }
    return lo;
}

#define FXS     514
#define FHS     65
#define MLDS    99072
#define RSTRIDE 128     // uint2 slots per row record (1 KB)

// ---------------- prep: per-row records, 8-way (act x src) sorted, hdr packed ----------------
// record slot 0: .x = c1|c2<<8|c3<<16|c4<<24  .y = c5|c6<<8|c7<<16|n<<24  (cumulative bounds)
// slots 1..n: .x = LDS offset (X: col ; H: (col-512)*65)  .y = prescaled weight bits
__global__ __launch_bounds__(512)
void prep_rows(const int* __restrict__ rows_h, const int* __restrict__ cols_h,
               const int* __restrict__ acts_h, const float* __restrict__ wh,
               const int* __restrict__ rows_o, const int* __restrict__ cols_o,
               const int* __restrict__ acts_o, const float* __restrict__ wo,
               int Eh, int Eo, uint2* __restrict__ rrh, uint2* __restrict__ rro)
{
    const int lane = (int)(threadIdx.x & 63);
    const int wid  = (int)((blockIdx.x * 512 + threadIdx.x) >> 6);
    if (wid >= NH + NO) return;
    const bool isH = wid < NH;
    const int r = isH ? wid : wid - NH;
    const int*   rows = isH ? rows_h : rows_o;
    const int*   cols = isH ? cols_h : cols_o;
    const int*   acts = isH ? acts_h : acts_o;
    const float* ww   = isH ? wh : wo;
    const int    E    = isH ? Eh : Eo;
    uint2* rec = (isH ? rrh : rro) + (size_t)r * RSTRIDE;

    const int e0 = lower_bound_dev(rows, E, r);
    const int e1 = lower_bound_dev(rows, E, r + 1);
    int n = e1 - e0; if (n > 127) n = 127;          // memory-safety clamp (unreachable)
    const unsigned long long lt = (1ull << lane) - 1ull;

    int cnt[8] = {0,0,0,0,0,0,0,0};
    for (int g = 0; g < n; g += 64) {
        int seg = -1;
        if (g + lane < n) {
            int e = e0 + g + lane;
            int a = acts[e];
            int col = cols[e];
            seg = (a - 1) + ((!isH && col >= IN_DIM) ? 4 : 0);
        }
        #pragma unroll
        for (int s = 0; s < 8; ++s) cnt[s] += __popcll(__ballot(seg == s));
    }
    int cum[9]; cum[0] = 0;
    #pragma unroll
    for (int s = 0; s < 8; ++s) cum[s + 1] = cum[s] + cnt[s];
    if (lane == 0) {
        unsigned hx = (unsigned)cum[1] | ((unsigned)cum[2] << 8) | ((unsigned)cum[3] << 16) | ((unsigned)cum[4] << 24);
        unsigned hy = (unsigned)cum[5] | ((unsigned)cum[6] << 8) | ((unsigned)cum[7] << 16) | ((unsigned)n << 24);
        rec[0] = make_uint2(hx, hy);
    }
    int pos[8];
    #pragma unroll
    for (int s = 0; s < 8; ++s) pos[s] = cum[s];
    for (int g = 0; g < n; g += 64) {
        int seg = -1; unsigned offv = 0, wbits = 0;
        if (g + lane < n) {
            int e = e0 + g + lane;
            int a = acts[e];
            int col = cols[e];
            bool hs = (!isH && col >= IN_DIM);
            seg = (a - 1) + (hs ? 4 : 0);
            offv = hs ? (unsigned)((col - IN_DIM) * FHS) : (unsigned)col;
            float w = ww[e];
            float ws = (a == 2) ? (2.f * L2E) * w : ((a == 4) ? -L2E * w : w);
            wbits = __float_as_uint(ws);
        }
        #pragma unroll
        for (int s = 0; s < 8; ++s) {
            unsigned long long m = __ballot(seg == s);
            if (seg == s) {
                int slot = 1 + pos[s] + __popcll(m & lt);
                rec[slot] = make_uint2(offv, wbits);
            }
            pos[s] += __popcll(m);
        }
    }
}

// ---------------- fused main ----------------
// LDS: X bf16 [64][514] = 65792 B + Hf f32 [128][65] = 33280 B -> 99072 B.
// Per row: one coalesced uint2 record load (prefetched), boundaries via readlane,
// 8 branch-free compile-time segments. DS is the only lgkm user in the hot loop.
template<int ACT, bool HSRC>
__device__ __forceinline__ void seg_run(float& acc, const unsigned short* __restrict__ X,
                                        const float* __restrict__ Hf,
                                        uint2 hv, int lo, int hi, int lane)
{
    #pragma unroll 2
    for (int j = lo; j < hi; ++j) {
        int soff = rdl((int)hv.x, j + 1);
        float w  = __uint_as_float((unsigned)rdl((int)hv.y, j + 1));
        float v;
        if (HSRC) v = Hf[soff + lane];
        else      v = bf2f(X[lane * FXS + soff]);
        if (ACT == 1)      acc = fmaf(v, w, acc);
        else if (ACT == 2) { float ex = fast_exp2(v * w); acc += 1.f - 2.f * fast_rcp(1.f + ex); }
        else if (ACT == 3) acc += fmaxf(v * w, 0.f);
        else               { float ex = fast_exp2(v * w); acc += fast_rcp(1.f + ex); }
    }
}

template<bool OUT>
__device__ __forceinline__ float row_body(uint2 hv, const uint2* __restrict__ grow,
                                          const unsigned short* __restrict__ X,
                                          const float* __restrict__ Hf, int lane)
{
    const int ux = rdl((int)hv.x, 0), uy = rdl((int)hv.y, 0);
    const int c1 = ux & 255, c2 = (ux >> 8) & 255, c3 = (ux >> 16) & 255, c4 = (int)((unsigned)ux >> 24);
    const int c5 = uy & 255, c6 = (uy >> 8) & 255, c7 = (uy >> 16) & 255, n  = (int)((unsigned)uy >> 24);
    float acc = 0.f;
    if (n <= 63) {
        seg_run<1,false>(acc, X, Hf, hv, 0,  c1, lane);
        seg_run<2,false>(acc, X, Hf, hv, c1, c2, lane);
        seg_run<3,false>(acc, X, Hf, hv, c2, c3, lane);
        seg_run<4,false>(acc, X, Hf, hv, c3, c4, lane);
        if (OUT) {
            seg_run<1,true>(acc, X, Hf, hv, c4, c5, lane);
            seg_run<2,true>(acc, X, Hf, hv, c5, c6, lane);
            seg_run<3,true>(acc, X, Hf, hv, c6, c7, lane);
            seg_run<4,true>(acc, X, Hf, hv, c7, n,  lane);
        }
    } else {
        // unreachable in practice (P < 1e-12): uniform global walk of the record
        for (int j = 0; j < n; ++j) {
            int soff = rfl((int)grow[1 + j].x);
            float w  = __int_as_float(rfl((int)grow[1 + j].y));
            int seg = (j < c1) ? 0 : (j < c2) ? 1 : (j < c3) ? 2 : (j < c4) ? 3
                    : (j < c5) ? 4 : (j < c6) ? 5 : (j < c7) ? 6 : 7;
            float v = (seg >= 4) ? Hf[soff + lane] : bf2f(X[lane * FXS + soff]);
            int a = (seg & 3) + 1;
            if (a == 1) acc = fmaf(v, w, acc);
            else if (a == 2) { float ex = fast_exp2(v * w); acc += 1.f - 2.f * fast_rcp(1.f + ex); }
            else if (a == 3) acc += fmaxf(v * w, 0.f);
            else { float ex = fast_exp2(v * w); acc += fast_rcp(1.f + ex); }
        }
    }
    return acc;
}

__global__ __launch_bounds__(1024)
void fused_main(const float* __restrict__ x,
                const uint2* __restrict__ rrh, const uint2* __restrict__ rro,
                float* __restrict__ out)
{
    extern __shared__ char lds[];
    unsigned short* X  = (unsigned short*)lds;
    float*          Hf = (float*)(lds + 65792);
    const int tid  = (int)threadIdx.x;
    const int lane = tid & 63;
    const int wv   = tid >> 6;
    const int rb   = (int)blockIdx.x * 64;

    // ---- stage x slab -> bf16 X[64][514], coalesced float4 reads ----
    {
        const float4* xv = (const float4*)(x + (size_t)rb * IN_DIM);
        #pragma unroll
        for (int kk = 0; kk < 8; ++kk) {
            int v = tid + kk * 1024;
            int rr = v >> 7, i = v & 127;
            float4 f = xv[v];
            unsigned int lo = f2bf_rne(f.x) | (f2bf_rne(f.y) << 16);
            unsigned int hi = f2bf_rne(f.z) | (f2bf_rne(f.w) << 16);
            unsigned int* dst = (unsigned int*)&X[rr * FXS + i * 4];
            dst[0] = lo; dst[1] = hi;
        }
    }
    __syncthreads();

    // ---- hidden: wave wv -> rows wv*8..+7, record prefetch pipeline ----
    {
        uint2 hv = rrh[(size_t)(wv * 8) * RSTRIDE + lane];
        for (int q = 0; q < 8; ++q) {
            const int r = wv * 8 + q;
            uint2 hvn = hv;
            if (q < 7) hvn = rrh[(size_t)(r + 1) * RSTRIDE + lane];
            float acc = row_body<false>(hv, rrh + (size_t)r * RSTRIDE, X, Hf, lane);
            Hf[r * FHS + lane] = acc;
            hv = hvn;
        }
    }
    __syncthreads();

    // ---- output: wave wv -> rows wv*16..+15; direct float4 chunk writes ----
    // lanes write their own batch's 16B chunk; all 16 waves fill each 1KB row in L2.
    {
        uint2 hv = rro[(size_t)(wv * 16) * RSTRIDE + lane];
        #pragma unroll 1
        for (int qc = 0; qc < 4; ++qc) {
            float r4[4];
            #pragma unroll
            for (int qi = 0; qi < 4; ++qi) {
                const int q = qc * 4 + qi;
                const int r = wv * 16 + q;
                uint2 hvn = hv;
                if (q < 15) hvn = rro[(size_t)(r + 1) * RSTRIDE + lane];
                r4[qi] = fast_tanh(row_body<true>(hv, rro + (size_t)r * RSTRIDE, X, Hf, lane));
                hv = hvn;
            }
            *(float4*)&out[(size_t)(rb + lane) * NO + wv * 16 + qc * 4] =
                make_float4(r4[0], r4[1], r4[2], r4[3]);
        }
    }
}

// =============== fallback: single fused kernel, no workspace ===============
#define FT      1024
#define FBPB    64
#define FHS2    65
#define FOBTS   260
#define FLDS    (99072 + 1544)
__device__ __forceinline__ float edge_act2(float z, int a, float k) {
    float ex = fast_exp2(k * z);
    float rc = fast_rcp(1.f + ex);
    return (a == 2) ? (1.f - 2.f * rc) : ((a == 4) ? rc : ((a == 3) ? fmaxf(z, 0.f) : z));
}
__global__ __launch_bounds__(FT)
void wann_fused(const float* __restrict__ x,
                const int* __restrict__ rows_h, const int* __restrict__ cols_h,
                const int* __restrict__ acts_h, const float* __restrict__ wh,
                const int* __restrict__ rows_o, const int* __restrict__ cols_o,
                const int* __restrict__ acts_o, const float* __restrict__ wo,
                float* __restrict__ out, int Eh, int Eo)
{
    extern __shared__ char lds[];
    unsigned short* X   = (unsigned short*)lds;
    float*          H   = (float*)(lds + 65792);
    float*          OBT = (float*)lds;
    int*            offsH = (int*)(lds + 99072);
    int*            offsO = offsH + (NH + 1);
    const int tid  = threadIdx.x;
    const int lane = tid & 63;
    const int wv   = tid >> 6;
    const int rb   = blockIdx.x * FBPB;
    const int* wh_i = (const int*)wh;
    const int* wo_i = (const int*)wo;
    {
        const float4* xv = (const float4*)(x + (size_t)rb * IN_DIM);
        #pragma unroll
        for (int kk = 0; kk < (FBPB * IN_DIM / 4) / FT; ++kk) {
            int v = tid + kk * FT;
            int r = v >> 7, i = v & 127;
            float4 f = xv[v];
            unsigned int lo = (unsigned int)f2bf16s(f.x) | ((unsigned int)f2bf16s(f.y) << 16);
            unsigned int hi = (unsigned int)f2bf16s(f.z) | ((unsigned int)f2bf16s(f.w) << 16);
            unsigned int* dst = (unsigned int*)&X[r * FXS + i * 4];
            dst[0] = lo; dst[1] = hi;
        }
    }
    if (tid <= NH) offsH[tid] = lower_bound_dev(rows_h, Eh, tid);
    else if (tid <= NH + 1 + NO) offsO[tid - (NH + 1)] = lower_bound_dev(rows_o, Eo, tid - (NH + 1));
    __syncthreads();
    for (int r = wv * (NH / 16); r < (wv + 1) * (NH / 16); ++r) {
        const int e0 = rfl(offsH[r]); const int e1 = rfl(offsH[r + 1]);
        float acc = 0.f;
        #pragma unroll 4
        for (int e = e0; e < e1; ++e) {
            int col = rfl(cols_h[e]); int a = rfl(acts_h[e]);
            float w = __int_as_float(rfl(wh_i[e]));
            acc += edge_act2(bf2f(X[lane * FXS + col]) * w, a, act_k(a));
        }
        H[r * FHS2 + lane] = acc;
    }
    __syncthreads();
    float res[NO / 16];
    #pragma unroll
    for (int rr = 0; rr < NO / 16; ++rr) {
        const int r = wv * (NO / 16) + rr;
        const int e0 = rfl(offsO[r]); const int e1 = rfl(offsO[r + 1]);
        float acc = 0.f;
        #pragma unroll 4
        for (int e = e0; e < e1; ++e) {
            int col = rfl(cols_o[e]); int a = rfl(acts_o[e]);
            float w = __int_as_float(rfl(wo_i[e]));
            float v = (col < IN_DIM) ? bf2f(X[lane * FXS + col]) : H[(col - IN_DIM) * FHS2 + lane];
            acc += edge_act2(v * w, a, act_k(a));
        }
        res[rr] = fast_tanh(acc);
    }
    __syncthreads();
    #pragma unroll
    for (int rr = 0; rr < NO / 16; ++rr)
        OBT[lane * FOBTS + wv * (NO / 16) + rr] = res[rr];
    __syncthreads();
    #pragma unroll
    for (int kk = 0; kk < (FBPB * NO / 4) / FT; ++kk) {
        int v = tid + kk * FT;
        int c4 = v & 63, b = v >> 6;
        float4 o = *(const float4*)&OBT[b * FOBTS + c4 * 4];
        *(float4*)&out[(size_t)(rb + b) * NO + c4 * 4] = o;
    }
}

extern "C" void kernel_launch(void* const* d_in, const int* in_sizes, int n_in,
                              void* d_out, int out_size, void* d_ws, size_t ws_size,
                              hipStream_t stream) {
    const float* x      = (const float*)d_in[0];
    const float* wh     = (const float*)d_in[1];
    const float* wo     = (const float*)d_in[2];
    const int*   rows_h = (const int*)d_in[3];
    const int*   cols_h = (const int*)d_in[4];
    const int*   acts_h = (const int*)d_in[5];
    const int*   rows_o = (const int*)d_in[6];
    const int*   cols_o = (const int*)d_in[7];
    const int*   acts_o = (const int*)d_in[8];
    float*       out    = (float*)d_out;

    const int Eh = in_sizes[1];
    const int Eo = in_sizes[2];

    // ws layout: [rrh: NH rows x 1KB][rro: NO rows x 1KB]
    char*  ws  = (char*)d_ws;
    uint2* rrh = (uint2*)ws;
    uint2* rro = (uint2*)(ws + (size_t)NH * RSTRIDE * 8);
    size_t need = (size_t)(NH + NO) * RSTRIDE * 8;

    if (ws_size >= need) {
        prep_rows<<<(NH + NO) * 64 / 512, 512, 0, stream>>>(
            rows_h, cols_h, acts_h, wh, rows_o, cols_o, acts_o, wo,
            Eh, Eo, rrh, rro);
        fused_main<<<BATCH / 64, 1024, MLDS, stream>>>(x, rrh, rro, out);
    } else {
        wann_fused<<<BATCH / FBPB, FT, FLDS, stream>>>(
            x, rows_h, cols_h, acts_h, wh, rows_o, cols_o, acts_o, wo, out, Eh, Eo);
    }
}